// Round 1
// baseline (709.257 us; speedup 1.0000x reference)
//
#include <hip/hip_runtime.h>

// RGATConv x2 (N=50000, E=800000, IN=HID=128, R=8) for MI355X/gfx950.
//
// Pipeline per graph:
//   1. xb = bf16(x)                                   [N,128]
//   2. Wb = bf16 B-fragment-packed W                  [R,4kk,8nt,64lane,8j]
//   3. Wq[r]=W_r@q, Wk[r]=W_r@k  (folds the attention dots into x-space)
//   4. s_q[n,r]=x_n.Wq[r], s_k[n,r]=x_n.Wk[r]
//   5. xt[r,n,:] = x_n @ W_r  via MFMA 16x16x32 bf16  (bf16 out, 102MB ws)
//   6. CSR by dst: histogram -> scan -> scatter (packed src*8|et)
//   7. aggregate: per-dst block: softmax over in-edges from s_q/s_k,
//      then out[c] = relu(b[c] + sum_e w_e * xt[et_e, src_e, c])

typedef unsigned short u16;
typedef __attribute__((ext_vector_type(8))) short short8;
typedef __attribute__((ext_vector_type(4))) float floatx4;

__device__ __forceinline__ u16 f2bf(float f) {
  union { float f; unsigned u; } v; v.f = f;
  unsigned r = v.u + 0x7FFFu + ((v.u >> 16) & 1u);  // RNE
  return (u16)(r >> 16);
}
__device__ __forceinline__ float bf2f(u16 u) {
  union { unsigned u; float f; } v; v.u = ((unsigned)u) << 16; return v.f;
}

// ---- 1. fp32 -> bf16 bulk convert -------------------------------------------
__global__ void k_f2bf(const float* __restrict__ x, u16* __restrict__ xb, int n) {
  int i = blockIdx.x * 256 + threadIdx.x;
  if (i < n) xb[i] = f2bf(x[i]);
}

// ---- 2. pack W into B-fragment order ----------------------------------------
// Wb[(((r*4+kk)*8+nt)*64+lane)*8+j] = bf16(W[r][kk*32+(lane>>4)*8+j][nt*16+(lane&15)])
__global__ void k_prep_wb(const float* __restrict__ W, u16* __restrict__ Wb, int R) {
  int t = blockIdx.x * 256 + threadIdx.x;
  int lane = t & 63, nt = (t >> 6) & 7, kk = (t >> 9) & 3, r = t >> 11;
  if (r >= R) return;
  int q = lane >> 4, m16 = lane & 15;
  int c = nt * 16 + m16;
  short8 v;
#pragma unroll
  for (int j = 0; j < 8; ++j) {
    int k = kk * 32 + q * 8 + j;
    v[j] = (short)f2bf(W[(r * 128 + k) * 128 + c]);
  }
  *(short8*)(Wb + (size_t)t * 8) = v;
}

// ---- 3. Wq[r][d] = sum_c W[r][d][c]*q[c]; Wk likewise -----------------------
__global__ void k_prep_wqk(const float* __restrict__ W, const float* __restrict__ qv,
                           const float* __restrict__ kv, float* __restrict__ Wq,
                           float* __restrict__ Wk, int R) {
  int wid = (blockIdx.x * 256 + threadIdx.x) >> 6;
  int lane = threadIdx.x & 63;
  if (wid >= R * 128) return;
  int r = wid >> 7, d = wid & 127;
  const float* row = W + ((size_t)(r * 128 + d)) * 128;
  float a0 = row[lane], a1 = row[lane + 64];
  float vq = a0 * qv[lane] + a1 * qv[lane + 64];
  float vk = a0 * kv[lane] + a1 * kv[lane + 64];
#pragma unroll
  for (int off = 32; off; off >>= 1) {
    vq += __shfl_xor(vq, off);
    vk += __shfl_xor(vk, off);
  }
  if (lane == 0) { Wq[wid] = vq; Wk[wid] = vk; }
}

// ---- 4. s_q[n][r], s_k[n][r] ------------------------------------------------
__global__ void k_sqk(const float* __restrict__ x, const float* __restrict__ Wq,
                      const float* __restrict__ Wk, float* __restrict__ sq,
                      float* __restrict__ sk, int N) {
  int wid = (blockIdx.x * 256 + threadIdx.x) >> 6;
  int lane = threadIdx.x & 63;
  if (wid >= N) return;
  float x0 = x[(size_t)wid * 128 + lane], x1 = x[(size_t)wid * 128 + 64 + lane];
#pragma unroll
  for (int r = 0; r < 8; ++r) {
    float vq = x0 * Wq[r * 128 + lane] + x1 * Wq[r * 128 + 64 + lane];
    float vk = x0 * Wk[r * 128 + lane] + x1 * Wk[r * 128 + 64 + lane];
#pragma unroll
    for (int off = 32; off; off >>= 1) {
      vq += __shfl_xor(vq, off);
      vk += __shfl_xor(vk, off);
    }
    if (lane == 0) { sq[wid * 8 + r] = vq; sk[wid * 8 + r] = vk; }
  }
}

// ---- 5. xt[r][n][c] = sum_d xb[n][d] * W[r][d][c]  (MFMA bf16) --------------
// block=256 (4 waves); wave w handles rows [blockIdx.x*64 + w*16, +16), all 128 cols.
__global__ void __launch_bounds__(256) k_gemm_xt(const u16* __restrict__ xb,
                                                 const u16* __restrict__ Wb,
                                                 u16* __restrict__ xt, int N) {
  int r = blockIdx.y;
  int wave = threadIdx.x >> 6, lane = threadIdx.x & 63;
  int m0 = blockIdx.x * 64 + wave * 16;
  int q = lane >> 4, m16 = lane & 15;
  int arow = m0 + m16; if (arow >= N) arow = N - 1;
  floatx4 acc[8];
#pragma unroll
  for (int nt = 0; nt < 8; ++nt) acc[nt] = (floatx4){0.f, 0.f, 0.f, 0.f};
#pragma unroll
  for (int kk = 0; kk < 4; ++kk) {
    short8 a = *(const short8*)(xb + (size_t)arow * 128 + kk * 32 + q * 8);
    const u16* wbp = Wb + ((size_t)((r * 4 + kk) * 8) * 64 + lane) * 8;
#pragma unroll
    for (int nt = 0; nt < 8; ++nt) {
      short8 b = *(const short8*)(wbp + nt * 512);
      acc[nt] = __builtin_amdgcn_mfma_f32_16x16x32_bf16(a, b, acc[nt], 0, 0, 0);
    }
  }
  // C/D layout: col = nt*16 + (lane&15), row = m0 + (lane>>4)*4 + reg
#pragma unroll
  for (int nt = 0; nt < 8; ++nt) {
    int c = nt * 16 + m16;
#pragma unroll
    for (int reg = 0; reg < 4; ++reg) {
      int row = m0 + q * 4 + reg;
      if (row < N) xt[((size_t)r * N + row) * 128 + c] = f2bf(acc[nt][reg]);
    }
  }
}

// ---- 6. CSR build -----------------------------------------------------------
__global__ void k_hist(const int* __restrict__ dst, int* __restrict__ cnt, int E) {
  int e = blockIdx.x * 256 + threadIdx.x;
  if (e < E) atomicAdd(&cnt[dst[e]], 1);
}

__global__ void k_scan_block(const int* __restrict__ cnt, int* __restrict__ excl,
                             int* __restrict__ bsum, int n) {
  __shared__ int sd[256];
  int tid = threadIdx.x;
  int base = blockIdx.x * 1024 + tid * 4;
  int v[4]; int tot = 0;
#pragma unroll
  for (int i = 0; i < 4; ++i) {
    int idx = base + i;
    v[i] = (idx < n) ? cnt[idx] : 0;
    tot += v[i];
  }
  sd[tid] = tot; __syncthreads();
  for (int off = 1; off < 256; off <<= 1) {
    int t = (tid >= off) ? sd[tid - off] : 0;
    __syncthreads();
    sd[tid] += t;
    __syncthreads();
  }
  int texcl = sd[tid] - tot;
  if (tid == 255) bsum[blockIdx.x] = sd[255];
  int run = texcl;
#pragma unroll
  for (int i = 0; i < 4; ++i) {
    int idx = base + i;
    if (idx < n) excl[idx] = run;
    run += v[i];
  }
}

__global__ void k_scan_top(int* __restrict__ bsum, int nb) {
  if (blockIdx.x == 0 && threadIdx.x == 0) {
    int run = 0;
    for (int i = 0; i < nb; ++i) { int t = bsum[i]; bsum[i] = run; run += t; }
  }
}

__global__ void k_scan_add(int* __restrict__ offs, int* __restrict__ cursor,
                           const int* __restrict__ bsum, int n, int total) {
  int i = blockIdx.x * 256 + threadIdx.x;
  if (i < n) {
    int vv = offs[i] + bsum[i >> 10];
    offs[i] = vv; cursor[i] = vv;
  }
  if (i == 0) offs[n] = total;
}

__global__ void k_scatter(const int* __restrict__ src, const int* __restrict__ dst,
                          const int* __restrict__ et, int* __restrict__ cursor,
                          int* __restrict__ csr, int E) {
  int e = blockIdx.x * 256 + threadIdx.x;
  if (e < E) {
    int slot = atomicAdd(&cursor[dst[e]], 1);
    csr[slot] = (src[e] << 3) | et[e];
  }
}

// ---- 7. per-dst softmax + weighted aggregation ------------------------------
__global__ void __launch_bounds__(128) k_aggregate(
    const int* __restrict__ csr, const int* __restrict__ offs,
    const float* __restrict__ sq, const float* __restrict__ sk,
    const u16* __restrict__ xt, const float* __restrict__ bias,
    float* __restrict__ out, int N) {
  __shared__ float red[128];
  __shared__ float wch[128];
  __shared__ int bch[128];
  int n = blockIdx.x, tid = threadIdx.x;
  int start = offs[n], end = offs[n + 1];
  const float* sqn = sq + n * 8;

  // pass 1: segment max of leaky_relu(alpha)
  float m = -INFINITY;
  for (int i = start + tid; i < end; i += 128) {
    int p = csr[i]; int s = p >> 3, e = p & 7;
    float a = sqn[e] + sk[s * 8 + e];
    a = (a > 0.f) ? a : 0.2f * a;
    m = fmaxf(m, a);
  }
  red[tid] = m; __syncthreads();
#pragma unroll
  for (int s = 64; s > 0; s >>= 1) {
    if (tid < s) red[tid] = fmaxf(red[tid], red[tid + s]);
    __syncthreads();
  }
  m = red[0]; __syncthreads();

  // pass 2: sum of exp
  float ssum = 0.f;
  for (int i = start + tid; i < end; i += 128) {
    int p = csr[i]; int s = p >> 3, e = p & 7;
    float a = sqn[e] + sk[s * 8 + e];
    a = (a > 0.f) ? a : 0.2f * a;
    ssum += __expf(a - m);
  }
  red[tid] = ssum; __syncthreads();
#pragma unroll
  for (int s = 64; s > 0; s >>= 1) {
    if (tid < s) red[tid] += red[tid + s];
    __syncthreads();
  }
  float inv = 1.f / (red[0] + 1e-16f); __syncthreads();

  // pass 3: out[c] = sum_e w_e * xt[et_e][src_e][c]
  float acc = 0.f;
  for (int base = start; base < end; base += 128) {
    int cntc = min(128, end - base);
    if (tid < cntc) {
      int p = csr[base + tid]; int s = p >> 3, e = p & 7;
      float a = sqn[e] + sk[s * 8 + e];
      a = (a > 0.f) ? a : 0.2f * a;
      wch[tid] = __expf(a - m) * inv;
      bch[tid] = (e * N + s) << 7;  // row base in xt (elements)
    }
    __syncthreads();
    for (int e = 0; e < cntc; ++e) {
      acc += wch[e] * bf2f(xt[(size_t)bch[e] + tid]);
    }
    __syncthreads();
  }
  out[(size_t)n * 128 + tid] = fmaxf(acc + bias[tid], 0.f);
}

// -----------------------------------------------------------------------------
extern "C" void kernel_launch(void* const* d_in, const int* in_sizes, int n_in,
                              void* d_out, int out_size, void* d_ws, size_t ws_size,
                              hipStream_t stream) {
  const float* x1 = (const float*)d_in[0];
  const int* ei1 = (const int*)d_in[1];
  const int* et1 = (const int*)d_in[2];
  const float* x2 = (const float*)d_in[3];
  const int* ei2 = (const int*)d_in[4];
  const int* et2 = (const int*)d_in[5];
  const float* W1 = (const float*)d_in[6];
  const float* q1 = (const float*)d_in[7];
  const float* k1 = (const float*)d_in[8];
  const float* b1 = (const float*)d_in[9];
  const float* W2 = (const float*)d_in[10];
  const float* q2 = (const float*)d_in[11];
  const float* k2 = (const float*)d_in[12];
  const float* b2 = (const float*)d_in[13];

  const int N = in_sizes[0] / 128;
  const int E = in_sizes[1] / 2;
  const int R = in_sizes[6] / (128 * 128);

  // workspace carve (256B aligned)
  size_t off = 0;
  char* w = (char*)d_ws;
  auto carve = [&](size_t bytes) -> void* {
    void* p = w + off;
    off += (bytes + 255) & ~(size_t)255;
    return p;
  };
  u16* xt = (u16*)carve((size_t)R * N * 128 * 2);
  u16* xb = (u16*)carve((size_t)N * 128 * 2);
  u16* Wb = (u16*)carve((size_t)R * 4 * 8 * 64 * 8 * 2);
  float* Wq = (float*)carve((size_t)R * 128 * 4);
  float* Wk = (float*)carve((size_t)R * 128 * 4);
  float* sq = (float*)carve((size_t)N * 8 * 4);
  float* sk = (float*)carve((size_t)N * 8 * 4);
  int* cnt = (int*)carve((size_t)(N + 1) * 4);
  int* offs = (int*)carve((size_t)(N + 1) * 4);
  int* cursor = (int*)carve((size_t)N * 4);
  int* bsum = (int*)carve(1024 * 4);
  int* csr = (int*)carve((size_t)E * 4);
  if (off > ws_size) return;  // insufficient workspace — fail visibly via absmax

  const int nscan = (N + 1023) / 1024;

  for (int g = 0; g < 2; ++g) {
    const float* x = g ? x2 : x1;
    const int* ei = g ? ei2 : ei1;
    const int* et = g ? et2 : et1;
    const float* W = g ? W2 : W1;
    const float* qv = g ? q2 : q1;
    const float* kv = g ? k2 : k1;
    const float* bv = g ? b2 : b1;
    float* outp = (float*)d_out + (size_t)g * N * 128;

    hipMemsetAsync(cnt, 0, (size_t)(N + 1) * 4, stream);
    k_f2bf<<<dim3((N * 128 + 255) / 256), dim3(256), 0, stream>>>(x, xb, N * 128);
    k_prep_wb<<<dim3((R * 2048 + 255) / 256), dim3(256), 0, stream>>>(W, Wb, R);
    k_prep_wqk<<<dim3((R * 128 * 64 + 255) / 256), dim3(256), 0, stream>>>(W, qv, kv, Wq, Wk, R);
    k_sqk<<<dim3((N * 64 + 255) / 256), dim3(256), 0, stream>>>(x, Wq, Wk, sq, sk, N);
    k_gemm_xt<<<dim3((N + 63) / 64, R), dim3(256), 0, stream>>>(xb, Wb, xt, N);
    k_hist<<<dim3((E + 255) / 256), dim3(256), 0, stream>>>(ei + E, cnt, E);
    k_scan_block<<<dim3(nscan), dim3(256), 0, stream>>>(cnt, offs, bsum, N);
    k_scan_top<<<dim3(1), dim3(64), 0, stream>>>(bsum, nscan);
    k_scan_add<<<dim3((N + 255) / 256), dim3(256), 0, stream>>>(offs, cursor, bsum, N, E);
    k_scatter<<<dim3((E + 255) / 256), dim3(256), 0, stream>>>(ei, ei + E, et, cursor, csr, E);
    k_aggregate<<<dim3(N), dim3(128), 0, stream>>>(csr, offs, sq, sk, xt, bv, outp, N);
  }
}